// Round 2
// baseline (1895.110 us; speedup 1.0000x reference)
//
#include <hip/hip_runtime.h>
#include <math.h>

#define E 1152
#define H 16
#define HD 72
#define B 32
#define S 4096
#define IDIM 4304

#define NEGF (-3.402823466e38f)
#define SCALE 0.1178511301977579f  // 1/sqrt(72)

__device__ __forceinline__ float wredsum(float v){
  v += __shfl_xor(v,32); v += __shfl_xor(v,16); v += __shfl_xor(v,8);
  v += __shfl_xor(v,4);  v += __shfl_xor(v,2);  v += __shfl_xor(v,1);
  return v;
}

// q[j] = probe . wq[j,:] + bq[j]
__global__ void k_q(const float* __restrict__ probe, const float* __restrict__ ipw,
                    const float* __restrict__ ipb, float* __restrict__ q){
  int tid = threadIdx.x, lane = tid & 63, w = tid >> 6;
  int j = blockIdx.x*4 + w;
  const float* wr = ipw + (size_t)j*E;
  float s = 0.f;
  #pragma unroll
  for (int t=0;t<18;++t){ int e = lane + 64*t; s = fmaf(probe[e], wr[e], s); }
  s = wredsum(s);
  if (lane==0) q[j] = s + ipb[j];
}

// qk[h*E+e] = sum_d q[h*72+d]*wk[h*72+d, e]; cb[h] = q[h]·bk_h
__global__ void k_qk(const float* __restrict__ q, const float* __restrict__ ipw,
                     const float* __restrict__ ipb, float* __restrict__ qk,
                     float* __restrict__ cb){
  int idx = blockIdx.x*256 + threadIdx.x;   // < H*E
  int h = idx / E, e = idx % E;
  float s = 0.f;
  #pragma unroll 8
  for (int d=0; d<HD; ++d)
    s = fmaf(q[h*HD+d], ipw[(size_t)(E + h*HD + d)*E + e], s);
  qk[idx] = s;
  if (idx < H){
    float c = 0.f;
    for (int d=0; d<HD; ++d) c = fmaf(q[idx*HD+d], ipb[E + idx*HD + d], c);
    cb[idx] = c;
  }
}

// ---------------- scores: sc[b][s][h] = SCALE*(hidden[b,s,:]·qk[h,:]+cb[h])+addmask
// 1024 blocks x 128 rows. Full qk (16 heads) staged once in 73.7KB LDS.
// Wave handles 4 rows/group, 8 groups, double-buffered row prefetch.
struct RowBuf { float2 v[4][9]; };

__device__ __forceinline__ void load_rows(RowBuf& rb, const float* __restrict__ hidden,
                                          int b, int r0, int lane){
  #pragma unroll
  for (int rr=0; rr<4; ++rr){
    const float2* hp = (const float2*)(hidden + ((size_t)b*S + r0 + rr)*E);
    #pragma unroll
    for (int k=0;k<9;++k) rb.v[rr][k] = hp[lane + 64*k];
  }
}

__device__ __forceinline__ void compute_store(const RowBuf& rb, const float* qk_lds,
                                              float cbv, const int* __restrict__ mask,
                                              float* __restrict__ sc,
                                              int b, int r0, int lane){
  float sval = 0.f;
  #pragma unroll
  for (int hh=0; hh<2; ++hh){
    float acc[4][8];
    #pragma unroll
    for (int rr=0;rr<4;++rr)
      #pragma unroll
      for (int h=0;h<8;++h) acc[rr][h] = 0.f;
    #pragma unroll
    for (int k=0;k<9;++k){
      #pragma unroll
      for (int h=0;h<8;++h){
        const float2 qv = *(const float2*)(qk_lds + (size_t)(hh*8+h)*E + 2*(lane + 64*k));
        #pragma unroll
        for (int rr=0;rr<4;++rr){
          acc[rr][h] = fmaf(rb.v[rr][k].x, qv.x, acc[rr][h]);
          acc[rr][h] = fmaf(rb.v[rr][k].y, qv.y, acc[rr][h]);
        }
      }
    }
    #pragma unroll
    for (int rr=0;rr<4;++rr)
      #pragma unroll
      for (int h=0;h<8;++h){
        float v = wredsum(acc[rr][h]);
        if (lane == rr*16 + hh*8 + h) sval = v;
      }
  }
  int rr = lane >> 4;
  int row = r0 + rr;
  float addm = (1.0f - (float)mask[(size_t)b*S + row]) * NEGF;
  sc[((size_t)b*S + r0)*H + lane] = SCALE*(sval + cbv) + addm;
}

__global__ __launch_bounds__(256) void k_scores(
    const float* __restrict__ hidden, const float* __restrict__ qk,
    const float* __restrict__ cb, const int* __restrict__ mask,
    float* __restrict__ sc){
  __shared__ float qk_lds[H*E];   // 73728 B
  int tid = threadIdx.x, lane = tid & 63, w = tid >> 6;
  {
    const float4* src = (const float4*)qk;
    float4* dst = (float4*)qk_lds;
    for (int i = tid; i < H*E/4; i += 256) dst[i] = src[i];
  }
  __syncthreads();
  int b  = blockIdx.x >> 5;
  int s0 = (blockIdx.x & 31) * 128;
  float cbv = cb[lane & 15];

  RowBuf hv, hn;
  load_rows(hv, hidden, b, s0 + w*4, lane);
  #pragma unroll
  for (int g = 0; g < 8; g += 2){
    if (g+1 < 8) load_rows(hn, hidden, b, s0 + (g+1)*16 + w*4, lane);
    compute_store(hv, qk_lds, cbv, mask, sc, b, s0 + g*16 + w*4, lane);
    if (g+2 < 8) load_rows(hv, hidden, b, s0 + (g+2)*16 + w*4, lane);
    compute_store(hn, qk_lds, cbv, mask, sc, b, s0 + (g+1)*16 + w*4, lane);
  }
}

// ---------------- m/l reduction over s, per (b,h)
// grid 32b x 8 chunks (512 s each). part_ml[(b*8+c)*16+h][2] = {m, l}
__global__ __launch_bounds__(256) void k_mlred(const float* __restrict__ sc,
                                               float* __restrict__ part_ml){
  __shared__ float red[4][16][2];
  int tid = threadIdx.x, lane = tid & 63, w = tid >> 6;
  int b = blockIdx.x >> 3, c = blockIdx.x & 7;
  int h = tid & 15, srow = tid >> 4;     // srow 0..15
  float m = -INFINITY, l = 0.f;
  for (int k = 0; k < 32; ++k){
    int s = c*512 + srow + 16*k;
    float v = sc[((size_t)b*S + s)*H + h];
    if (v > m){ l *= __expf(m - v); m = v; }
    l += __expf(v - m);
  }
  #pragma unroll
  for (int d = 16; d < 64; d <<= 1){
    float om = __shfl_xor(m, d), ol = __shfl_xor(l, d);
    float nm = fmaxf(m, om);
    l = l*__expf(m - nm) + ol*__expf(om - nm);
    m = nm;
  }
  if (lane < 16){ red[w][lane][0] = m; red[w][lane][1] = l; }
  __syncthreads();
  if (tid < 16){
    float M = red[0][tid][0], L = red[0][tid][1];
    #pragma unroll
    for (int ww=1; ww<4; ++ww){
      float om = red[ww][tid][0], ol = red[ww][tid][1];
      float nm = fmaxf(M, om);
      L = L*__expf(M - nm) + ol*__expf(om - nm);
      M = nm;
    }
    size_t o = ((size_t)(b*8 + c)*16 + tid)*2;
    part_ml[o] = M; part_ml[o+1] = L;
  }
}

// 1 block: combine 8 chunks -> ml[b*32+h]=m, ml[b*32+16+h]=l
__global__ void k_mlcomb(const float* __restrict__ part_ml, float* __restrict__ ml){
  int t = threadIdx.x;            // 512 = 32*16
  int b = t >> 4, h = t & 15;
  float M = -INFINITY, L = 0.f;
  #pragma unroll
  for (int c = 0; c < 8; ++c){
    size_t o = ((size_t)(b*8 + c)*16 + h)*2;
    float om = part_ml[o], ol = part_ml[o+1];
    float nm = fmaxf(M, om);
    L = L*__expf(M - nm) + ol*__expf(om - nm);
    M = nm;
  }
  ml[b*32 + h] = M; ml[b*32 + 16 + h] = L;
}

// ---------------- ctx partials: wave owns 4 heads, lane owns e-slice (float2)
// grid 32b x slices; weights exp(sc-m)/l computed inline from raw scores.
__global__ __launch_bounds__(256) void k_ctx(
    const float* __restrict__ hidden, const float* __restrict__ sc,
    const float* __restrict__ ml, float* __restrict__ part,
    int slices, int s_per){
  int tid = threadIdx.x, lane = tid & 63, w = tid >> 6;
  int b = blockIdx.x / slices, sl = blockIdx.x % slices;
  float mh[4], invl[4];
  #pragma unroll
  for (int j=0;j<4;++j){
    mh[j]   = ml[b*32 + w*4 + j];
    invl[j] = 1.0f / ml[b*32 + 16 + w*4 + j];
  }
  float2 acc[4][9];
  #pragma unroll
  for (int j=0;j<4;++j)
    #pragma unroll
    for (int k=0;k<9;++k){ acc[j][k].x = 0.f; acc[j][k].y = 0.f; }

  int sbeg = sl * s_per;
  #pragma unroll 2
  for (int s = sbeg; s < sbeg + s_per; ++s){
    const float2* hp = (const float2*)(hidden + ((size_t)b*S + s)*E);
    float2 hvv[9];
    #pragma unroll
    for (int k=0;k<9;++k) hvv[k] = hp[lane + 64*k];
    const float4 scv = *(const float4*)(sc + ((size_t)b*S + s)*H + w*4);
    float wgt[4];
    wgt[0] = __expf(scv.x - mh[0]) * invl[0];
    wgt[1] = __expf(scv.y - mh[1]) * invl[1];
    wgt[2] = __expf(scv.z - mh[2]) * invl[2];
    wgt[3] = __expf(scv.w - mh[3]) * invl[3];
    #pragma unroll
    for (int j=0;j<4;++j)
      #pragma unroll
      for (int k=0;k<9;++k){
        acc[j][k].x = fmaf(wgt[j], hvv[k].x, acc[j][k].x);
        acc[j][k].y = fmaf(wgt[j], hvv[k].y, acc[j][k].y);
      }
  }
  #pragma unroll
  for (int j=0;j<4;++j){
    float2* dst = (float2*)(part + ((size_t)(b*slices + sl)*H + w*4 + j)*E);
    #pragma unroll
    for (int k=0;k<9;++k) dst[lane + 64*k] = acc[j][k];
  }
}

// ctx[b][h][e] = sum_sl part[b][sl][h][e]
__global__ void k_ctxred(const float* __restrict__ part, float* __restrict__ ctx, int slices){
  int idx = blockIdx.x*256 + threadIdx.x;  // < B*H*E
  int b = idx / (H*E); int he = idx % (H*E);
  float s = 0.f;
  for (int sl=0; sl<slices; ++sl) s += part[((size_t)(b*slices+sl))*(H*E) + he];
  ctx[idx] = s;
}

// pooled[b, j] = wv[j,:]·ctx[b, j/72, :] + bv[j]
__global__ void k_pool(const float* __restrict__ ctx, const float* __restrict__ ipw,
                       const float* __restrict__ ipb, float* __restrict__ pooled){
  int tid = threadIdx.x, lane = tid & 63, w = tid >> 6;
  int j = blockIdx.x*4 + w;
  int h = j / HD;
  const float* wr = ipw + (size_t)2*E*E + (size_t)j*E;
  float acc[32];
  #pragma unroll
  for (int b_=0;b_<32;++b_) acc[b_]=0.f;
  #pragma unroll
  for (int t=0;t<18;++t){
    int e = lane + 64*t;
    float wv = wr[e];
    #pragma unroll
    for (int b_=0;b_<32;++b_)
      acc[b_] = fmaf(wv, ctx[(size_t)(b_*H + h)*E + e], acc[b_]);
  }
  #pragma unroll
  for (int b_=0;b_<32;++b_){
    float s = wredsum(acc[b_]);
    if (lane==b_) pooled[(size_t)b_*E + j] = s + ipb[2*E + j];
  }
}

__global__ void k_outproj(const float* __restrict__ pooled, const float* __restrict__ ow,
                          const float* __restrict__ ob, float* __restrict__ resid){
  int tid = threadIdx.x, lane = tid & 63, w = tid >> 6;
  int i = blockIdx.x*4 + w;
  const float* wr = ow + (size_t)i*E;
  float acc[32];
  #pragma unroll
  for (int b_=0;b_<32;++b_) acc[b_]=0.f;
  #pragma unroll
  for (int t=0;t<18;++t){
    int e = lane + 64*t;
    float wv = wr[e];
    #pragma unroll
    for (int b_=0;b_<32;++b_)
      acc[b_] = fmaf(wv, pooled[(size_t)b_*E + e], acc[b_]);
  }
  #pragma unroll
  for (int b_=0;b_<32;++b_){
    float s = wredsum(acc[b_]);
    if (lane==b_) resid[(size_t)b_*E + i] = s + ob[i];
  }
}

__global__ void k_ln(const float* __restrict__ resid, const float* __restrict__ g,
                     const float* __restrict__ be, float* __restrict__ x){
  __shared__ float red[8];
  int b = blockIdx.x, tid = threadIdx.x, lane = tid & 63, w = tid >> 6;
  const float* r = resid + (size_t)b*E;
  float s = 0.f, s2 = 0.f;
  for (int e=tid; e<E; e+=256){ float v = r[e]; s += v; s2 = fmaf(v,v,s2); }
  s = wredsum(s); s2 = wredsum(s2);
  if (lane==0){ red[w]=s; red[4+w]=s2; }
  __syncthreads();
  float S1 = red[0]+red[1]+red[2]+red[3];
  float S2 = red[4]+red[5]+red[6]+red[7];
  float mu  = S1*(1.0f/E);
  float var = S2*(1.0f/E) - mu*mu;
  float inv = rsqrtf(var + 1e-6f);
  for (int e=tid; e<E; e+=256){
    float v = (r[e]-mu)*inv;
    x[(size_t)b*E + e] = v*g[e] + be[e];
  }
}

__device__ __forceinline__ float gelu_tanh(float u){
  float u3 = u*u*u;
  float t = tanhf(0.7978845608028654f*(u + 0.044715f*u3));
  return 0.5f*u*(1.0f+t);
}

__global__ __launch_bounds__(256) void k_fc1(
    const float* __restrict__ x, const float* __restrict__ w1,
    const float* __restrict__ b1, float* __restrict__ h1){
  int tid = threadIdx.x, lane = tid & 63, w = tid >> 6;
  int wid = blockIdx.x*4 + w;      // < 2152
  int i0 = wid*2;
  float acc[2][32];
  #pragma unroll
  for (int ii=0;ii<2;++ii)
    #pragma unroll
    for (int b_=0;b_<32;++b_) acc[ii][b_]=0.f;
  #pragma unroll
  for (int t=0;t<18;++t){
    int e = lane + 64*t;
    float f0 = w1[(size_t)i0*E + e];
    float f1 = w1[(size_t)(i0+1)*E + e];
    #pragma unroll
    for (int b_=0;b_<32;++b_){
      float xv = x[(size_t)b_*E + e];
      acc[0][b_] = fmaf(f0, xv, acc[0][b_]);
      acc[1][b_] = fmaf(f1, xv, acc[1][b_]);
    }
  }
  #pragma unroll
  for (int ii=0;ii<2;++ii)
    #pragma unroll
    for (int b_=0;b_<32;++b_){
      float s = wredsum(acc[ii][b_]);
      if (lane==b_) h1[(size_t)b_*IDIM + i0 + ii] = gelu_tanh(s + b1[i0+ii]);
    }
}

__global__ __launch_bounds__(256) void k_fc2(
    const float* __restrict__ h1, const float* __restrict__ w2,
    const float* __restrict__ b2, const float* __restrict__ resid,
    float* __restrict__ out){
  int tid = threadIdx.x, lane = tid & 63, w = tid >> 6;
  int wid = blockIdx.x*4 + w;      // < 576
  int i0 = wid*2;
  float acc[2][32];
  #pragma unroll
  for (int ii=0;ii<2;++ii)
    #pragma unroll
    for (int b_=0;b_<32;++b_) acc[ii][b_]=0.f;
  #pragma unroll 2
  for (int t=0;t<68;++t){
    int e = lane + 64*t;
    if (e < IDIM){
      float f0 = w2[(size_t)i0*IDIM + e];
      float f1 = w2[(size_t)(i0+1)*IDIM + e];
      #pragma unroll
      for (int b_=0;b_<32;++b_){
        float hvv = h1[(size_t)b_*IDIM + e];
        acc[0][b_] = fmaf(f0, hvv, acc[0][b_]);
        acc[1][b_] = fmaf(f1, hvv, acc[1][b_]);
      }
    }
  }
  #pragma unroll
  for (int ii=0;ii<2;++ii)
    #pragma unroll
    for (int b_=0;b_<32;++b_){
      float s = wredsum(acc[ii][b_]);
      if (lane==b_){
        int i = i0 + ii;
        out[(size_t)b_*E + i] = resid[(size_t)b_*E + i] + s + b2[i];
      }
    }
}

extern "C" void kernel_launch(void* const* d_in, const int* in_sizes, int n_in,
                              void* d_out, int out_size, void* d_ws, size_t ws_size,
                              hipStream_t stream){
  const float* hidden = (const float*)d_in[0];
  const int*   mask   = (const int*)d_in[1];
  const float* probe  = (const float*)d_in[2];
  const float* ipw    = (const float*)d_in[3];
  const float* ipb    = (const float*)d_in[4];
  const float* ow     = (const float*)d_in[5];
  const float* ob     = (const float*)d_in[6];
  const float* ln_g   = (const float*)d_in[7];
  const float* ln_b   = (const float*)d_in[8];
  const float* w1     = (const float*)d_in[9];
  const float* b1     = (const float*)d_in[10];
  const float* w2     = (const float*)d_in[11];
  const float* b2     = (const float*)d_in[12];
  float* out = (float*)d_out;
  float* ws  = (float*)d_ws;

  size_t off = 0;
  float* q  = ws + off; off += E;          // 1152
  float* qk = ws + off; off += H*E;        // 18432
  float* cb = ws + off; off += 16;         // 16
  float* sc = ws + off; off += (size_t)B*S*H;       // 2097152
  float* part_ml = ws + off; off += 32*8*16*2;      // 8192
  float* ml = ws + off; off += 32*32;               // 1024

  int slices = 32;
  while (slices > 1){
    size_t need = off + (size_t)B*slices*H*E + (size_t)B*H*E
                + 3*(size_t)B*E + (size_t)B*IDIM;
    if (need*sizeof(float) <= ws_size) break;
    slices >>= 1;
  }
  float* part   = ws + off;  off += (size_t)B*slices*H*E;
  float* ctx    = ws + off;  off += (size_t)B*H*E;
  float* pooled = ws + off;  off += (size_t)B*E;
  float* resid  = ws + off;  off += (size_t)B*E;
  float* x      = ws + off;  off += (size_t)B*E;
  float* h1     = ws + off;

  k_q       <<<288, 256, 0, stream>>>(probe, ipw, ipb, q);
  k_qk      <<<72, 256, 0, stream>>>(q, ipw, ipb, qk, cb);
  k_scores  <<<1024, 256, 0, stream>>>(hidden, qk, cb, mask, sc);
  k_mlred   <<<256, 256, 0, stream>>>(sc, part_ml);
  k_mlcomb  <<<1, 512, 0, stream>>>(part_ml, ml);
  k_ctx     <<<32*slices, 256, 0, stream>>>(hidden, sc, ml, part, slices, S/slices);
  k_ctxred  <<<2304, 256, 0, stream>>>(part, ctx, slices);
  k_pool    <<<288, 256, 0, stream>>>(ctx, ipw, ipb, pooled);
  k_outproj <<<288, 256, 0, stream>>>(pooled, ow, ob, resid);
  k_ln      <<<32, 256, 0, stream>>>(resid, ln_g, ln_b, x);
  k_fc1     <<<538, 256, 0, stream>>>(x, w1, b1, h1);
  k_fc2     <<<144, 256, 0, stream>>>(h1, w2, b2, resid, out);
}

// Round 3
// 1238.305 us; speedup vs baseline: 1.5304x; 1.5304x over previous
//
#include <hip/hip_runtime.h>
#include <math.h>

#define E 1152
#define H 16
#define HD 72
#define B 32
#define S 4096
#define IDIM 4304

#define NEGF (-3.402823466e38f)
#define SCALE 0.1178511301977579f  // 1/sqrt(72)

__device__ __forceinline__ float wredsum(float v){
  v += __shfl_xor(v,32); v += __shfl_xor(v,16); v += __shfl_xor(v,8);
  v += __shfl_xor(v,4);  v += __shfl_xor(v,2);  v += __shfl_xor(v,1);
  return v;
}

// q[j] = probe . wq[j,:] + bq[j]
__global__ void k_q(const float* __restrict__ probe, const float* __restrict__ ipw,
                    const float* __restrict__ ipb, float* __restrict__ q){
  int tid = threadIdx.x, lane = tid & 63, w = tid >> 6;
  int j = blockIdx.x*4 + w;
  const float* wr = ipw + (size_t)j*E;
  float s = 0.f;
  #pragma unroll
  for (int t=0;t<18;++t){ int e = lane + 64*t; s = fmaf(probe[e], wr[e], s); }
  s = wredsum(s);
  if (lane==0) q[j] = s + ipb[j];
}

// qk[h*E+e] = sum_d q[h*72+d]*wk[h*72+d, e]; cb[h] = q[h]·bk_h
__global__ void k_qk(const float* __restrict__ q, const float* __restrict__ ipw,
                     const float* __restrict__ ipb, float* __restrict__ qk,
                     float* __restrict__ cb){
  int idx = blockIdx.x*256 + threadIdx.x;   // < H*E
  int h = idx / E, e = idx % E;
  float s = 0.f;
  #pragma unroll 8
  for (int d=0; d<HD; ++d)
    s = fmaf(q[h*HD+d], ipw[(size_t)(E + h*HD + d)*E + e], s);
  qk[idx] = s;
  if (idx < H){
    float c = 0.f;
    for (int d=0; d<HD; ++d) c = fmaf(q[idx*HD+d], ipb[E + idx*HD + d], c);
    cb[idx] = c;
  }
}

// ---------------- pass 1: scores + per-block (m,l) partials
// grid: 32 b x 32 slices; block = 4 waves; 128 rows/block, 16 stages of 8 rows.
// Wave w owns heads 4w..4w+3, qk for them in registers (72 VGPR).
// sc[b][s][h]; part_ml[(b*32+sl)*16+h] = {m,l} over the block's 128 rows.
__global__ __launch_bounds__(256) void k_scores(
    const float* __restrict__ hidden, const float* __restrict__ qk,
    const float* __restrict__ cb, const int* __restrict__ mask,
    float* __restrict__ sc, float* __restrict__ part_ml){
  __shared__ float tile[8*E];   // 36864 B
  int tid = threadIdx.x, lane = tid & 63, w = tid >> 6;
  int b = blockIdx.x >> 5, sl = blockIdx.x & 31;
  int s0 = sl*128;

  float2 qkr[4][9];
  #pragma unroll
  for (int j=0;j<4;++j){
    const float2* qp = (const float2*)(qk + (size_t)(4*w+j)*E);
    #pragma unroll
    for (int k=0;k<9;++k) qkr[j][k] = qp[lane + 64*k];
  }
  float cbv = cb[4*w + (lane & 3)];
  bool o1 = (lane & 1), o2 = (lane & 2);

  float m = -INFINITY, l = 0.f;

  for (int st=0; st<16; ++st){
    __syncthreads();
    {
      const float4* src = (const float4*)(hidden + ((size_t)b*S + s0 + st*8)*E);
      float4* dst = (float4*)tile;
      #pragma unroll
      for (int i=0;i<9;++i) dst[tid + 256*i] = src[tid + 256*i];
    }
    __syncthreads();
    #pragma unroll
    for (int r=0; r<8; ++r){
      const float2* row = (const float2*)(tile + r*E);
      float a0=0.f, a1=0.f, a2=0.f, a3=0.f;
      #pragma unroll
      for (int k=0;k<9;++k){
        float2 hv = row[lane + 64*k];
        a0 = fmaf(hv.x, qkr[0][k].x, fmaf(hv.y, qkr[0][k].y, a0));
        a1 = fmaf(hv.x, qkr[1][k].x, fmaf(hv.y, qkr[1][k].y, a1));
        a2 = fmaf(hv.x, qkr[2][k].x, fmaf(hv.y, qkr[2][k].y, a2));
        a3 = fmaf(hv.x, qkr[3][k].x, fmaf(hv.y, qkr[3][k].y, a3));
      }
      // packed 4-value butterfly: lane&3 == j ends with head (4w+j) sum
      float c01 = o1 ? a1 : a0, d01 = o1 ? a0 : a1;
      c01 += __shfl_xor(d01, 1);
      float c23 = o1 ? a3 : a2, d23 = o1 ? a2 : a3;
      c23 += __shfl_xor(d23, 1);
      float v = o2 ? c23 : c01, dv = o2 ? c01 : c23;
      v += __shfl_xor(dv, 2);
      v += __shfl_xor(v,4); v += __shfl_xor(v,8);
      v += __shfl_xor(v,16); v += __shfl_xor(v,32);

      int s = s0 + st*8 + r;
      float addm = (1.0f - (float)mask[(size_t)b*S + s]) * NEGF;
      v = SCALE*(v + cbv) + addm;
      // online (m,l) per head (identical across lanes of same lane&3 class)
      if (v > m){ l *= __expf(m - v); m = v; }
      l += __expf(v - m);
      if (lane < 4) sc[((size_t)b*S + s)*H + 4*w + lane] = v;
    }
  }
  if (lane < 4){
    size_t o = ((size_t)(b*32 + sl)*16 + 4*w + lane)*2;
    part_ml[o] = m; part_ml[o+1] = l;
  }
}

// 1 block: combine 32 slice-partials -> ml[b*32+h]=m, ml[b*32+16+h]=l
__global__ void k_mlcomb(const float* __restrict__ part_ml, float* __restrict__ ml){
  int t = threadIdx.x;            // 512 = 32*16
  int b = t >> 4, h = t & 15;
  float M = -INFINITY, L = 0.f;
  for (int c = 0; c < 32; ++c){
    size_t o = ((size_t)(b*32 + c)*16 + h)*2;
    float om = part_ml[o], ol = part_ml[o+1];
    float nm = fmaxf(M, om);
    L = L*__expf(M - nm) + ol*__expf(om - nm);
    M = nm;
  }
  ml[b*32 + h] = M; ml[b*32 + 16 + h] = L;
}

// ---------------- pass 2: ctx partials. Same staging; wave w owns heads 4w..4w+3.
// part[b][sl][h][e] = sum_{s in slice} softmax_w * hidden[b,s,e]
__global__ __launch_bounds__(256) void k_ctx(
    const float* __restrict__ hidden, const float* __restrict__ sc,
    const float* __restrict__ ml, float* __restrict__ part,
    int slices, int s_per){
  __shared__ float tile[8*E];
  int tid = threadIdx.x, lane = tid & 63, w = tid >> 6;
  int b = blockIdx.x / slices, sl = blockIdx.x % slices;
  int s0 = sl * s_per;
  float mh[4], invl[4];
  #pragma unroll
  for (int j=0;j<4;++j){
    mh[j]   = ml[b*32 + 4*w + j];
    invl[j] = 1.0f / ml[b*32 + 16 + 4*w + j];
  }
  float2 acc[4][9];
  #pragma unroll
  for (int j=0;j<4;++j)
    #pragma unroll
    for (int k=0;k<9;++k){ acc[j][k].x = 0.f; acc[j][k].y = 0.f; }

  int stages = s_per >> 3;
  for (int st=0; st<stages; ++st){
    __syncthreads();
    {
      const float4* src = (const float4*)(hidden + ((size_t)b*S + s0 + st*8)*E);
      float4* dst = (float4*)tile;
      #pragma unroll
      for (int i=0;i<9;++i) dst[tid + 256*i] = src[tid + 256*i];
    }
    __syncthreads();
    #pragma unroll
    for (int r=0; r<8; ++r){
      int s = s0 + st*8 + r;
      const float4 scv = *(const float4*)(sc + ((size_t)b*S + s)*H + 4*w);
      float w0 = __expf(scv.x - mh[0]) * invl[0];
      float w1 = __expf(scv.y - mh[1]) * invl[1];
      float w2 = __expf(scv.z - mh[2]) * invl[2];
      float w3 = __expf(scv.w - mh[3]) * invl[3];
      const float2* row = (const float2*)(tile + r*E);
      #pragma unroll
      for (int k=0;k<9;++k){
        float2 hv = row[lane + 64*k];
        acc[0][k].x = fmaf(w0, hv.x, acc[0][k].x); acc[0][k].y = fmaf(w0, hv.y, acc[0][k].y);
        acc[1][k].x = fmaf(w1, hv.x, acc[1][k].x); acc[1][k].y = fmaf(w1, hv.y, acc[1][k].y);
        acc[2][k].x = fmaf(w2, hv.x, acc[2][k].x); acc[2][k].y = fmaf(w2, hv.y, acc[2][k].y);
        acc[3][k].x = fmaf(w3, hv.x, acc[3][k].x); acc[3][k].y = fmaf(w3, hv.y, acc[3][k].y);
      }
    }
  }
  #pragma unroll
  for (int j=0;j<4;++j){
    float2* dst = (float2*)(part + ((size_t)(b*slices + sl)*H + 4*w + j)*E);
    #pragma unroll
    for (int k=0;k<9;++k) dst[lane + 64*k] = acc[j][k];
  }
}

// ctx[b][h][e] = sum_sl part[b][sl][h][e]
__global__ void k_ctxred(const float* __restrict__ part, float* __restrict__ ctx, int slices){
  int idx = blockIdx.x*256 + threadIdx.x;  // < B*H*E
  int b = idx / (H*E); int he = idx % (H*E);
  float s = 0.f;
  for (int sl=0; sl<slices; ++sl) s += part[((size_t)(b*slices+sl))*(H*E) + he];
  ctx[idx] = s;
}

// pooled[b, j] = wv[j,:]·ctx[b, j/72, :] + bv[j]
__global__ void k_pool(const float* __restrict__ ctx, const float* __restrict__ ipw,
                       const float* __restrict__ ipb, float* __restrict__ pooled){
  int tid = threadIdx.x, lane = tid & 63, w = tid >> 6;
  int j = blockIdx.x*4 + w;
  int h = j / HD;
  const float* wr = ipw + (size_t)2*E*E + (size_t)j*E;
  float acc[32];
  #pragma unroll
  for (int b_=0;b_<32;++b_) acc[b_]=0.f;
  #pragma unroll
  for (int t=0;t<18;++t){
    int e = lane + 64*t;
    float wv = wr[e];
    #pragma unroll
    for (int b_=0;b_<32;++b_)
      acc[b_] = fmaf(wv, ctx[(size_t)(b_*H + h)*E + e], acc[b_]);
  }
  #pragma unroll
  for (int b_=0;b_<32;++b_){
    float s = wredsum(acc[b_]);
    if (lane==b_) pooled[(size_t)b_*E + j] = s + ipb[2*E + j];
  }
}

__global__ void k_outproj(const float* __restrict__ pooled, const float* __restrict__ ow,
                          const float* __restrict__ ob, float* __restrict__ resid){
  int tid = threadIdx.x, lane = tid & 63, w = tid >> 6;
  int i = blockIdx.x*4 + w;
  const float* wr = ow + (size_t)i*E;
  float acc[32];
  #pragma unroll
  for (int b_=0;b_<32;++b_) acc[b_]=0.f;
  #pragma unroll
  for (int t=0;t<18;++t){
    int e = lane + 64*t;
    float wv = wr[e];
    #pragma unroll
    for (int b_=0;b_<32;++b_)
      acc[b_] = fmaf(wv, pooled[(size_t)b_*E + e], acc[b_]);
  }
  #pragma unroll
  for (int b_=0;b_<32;++b_){
    float s = wredsum(acc[b_]);
    if (lane==b_) resid[(size_t)b_*E + i] = s + ob[i];
  }
}

__global__ void k_ln(const float* __restrict__ resid, const float* __restrict__ g,
                     const float* __restrict__ be, float* __restrict__ x){
  __shared__ float red[8];
  int b = blockIdx.x, tid = threadIdx.x, lane = tid & 63, w = tid >> 6;
  const float* r = resid + (size_t)b*E;
  float s = 0.f, s2 = 0.f;
  for (int e=tid; e<E; e+=256){ float v = r[e]; s += v; s2 = fmaf(v,v,s2); }
  s = wredsum(s); s2 = wredsum(s2);
  if (lane==0){ red[w]=s; red[4+w]=s2; }
  __syncthreads();
  float S1 = red[0]+red[1]+red[2]+red[3];
  float S2 = red[4]+red[5]+red[6]+red[7];
  float mu  = S1*(1.0f/E);
  float var = S2*(1.0f/E) - mu*mu;
  float inv = rsqrtf(var + 1e-6f);
  for (int e=tid; e<E; e+=256){
    float v = (r[e]-mu)*inv;
    x[(size_t)b*E + e] = v*g[e] + be[e];
  }
}

__device__ __forceinline__ float gelu_tanh(float u){
  float u3 = u*u*u;
  float t = tanhf(0.7978845608028654f*(u + 0.044715f*u3));
  return 0.5f*u*(1.0f+t);
}

__global__ __launch_bounds__(256) void k_fc1(
    const float* __restrict__ x, const float* __restrict__ w1,
    const float* __restrict__ b1, float* __restrict__ h1){
  int tid = threadIdx.x, lane = tid & 63, w = tid >> 6;
  int wid = blockIdx.x*4 + w;      // < 2152
  int i0 = wid*2;
  float acc[2][32];
  #pragma unroll
  for (int ii=0;ii<2;++ii)
    #pragma unroll
    for (int b_=0;b_<32;++b_) acc[ii][b_]=0.f;
  #pragma unroll
  for (int t=0;t<18;++t){
    int e = lane + 64*t;
    float f0 = w1[(size_t)i0*E + e];
    float f1 = w1[(size_t)(i0+1)*E + e];
    #pragma unroll
    for (int b_=0;b_<32;++b_){
      float xv = x[(size_t)b_*E + e];
      acc[0][b_] = fmaf(f0, xv, acc[0][b_]);
      acc[1][b_] = fmaf(f1, xv, acc[1][b_]);
    }
  }
  #pragma unroll
  for (int ii=0;ii<2;++ii)
    #pragma unroll
    for (int b_=0;b_<32;++b_){
      float s = wredsum(acc[ii][b_]);
      if (lane==b_) h1[(size_t)b_*IDIM + i0 + ii] = gelu_tanh(s + b1[i0+ii]);
    }
}

__global__ __launch_bounds__(256) void k_fc2(
    const float* __restrict__ h1, const float* __restrict__ w2,
    const float* __restrict__ b2, const float* __restrict__ resid,
    float* __restrict__ out){
  int tid = threadIdx.x, lane = tid & 63, w = tid >> 6;
  int wid = blockIdx.x*4 + w;      // < 576
  int i0 = wid*2;
  float acc[2][32];
  #pragma unroll
  for (int ii=0;ii<2;++ii)
    #pragma unroll
    for (int b_=0;b_<32;++b_) acc[ii][b_]=0.f;
  #pragma unroll 2
  for (int t=0;t<68;++t){
    int e = lane + 64*t;
    if (e < IDIM){
      float f0 = w2[(size_t)i0*IDIM + e];
      float f1 = w2[(size_t)(i0+1)*IDIM + e];
      #pragma unroll
      for (int b_=0;b_<32;++b_){
        float hvv = h1[(size_t)b_*IDIM + e];
        acc[0][b_] = fmaf(f0, hvv, acc[0][b_]);
        acc[1][b_] = fmaf(f1, hvv, acc[1][b_]);
      }
    }
  }
  #pragma unroll
  for (int ii=0;ii<2;++ii)
    #pragma unroll
    for (int b_=0;b_<32;++b_){
      float s = wredsum(acc[ii][b_]);
      if (lane==b_){
        int i = i0 + ii;
        out[(size_t)b_*E + i] = resid[(size_t)b_*E + i] + s + b2[i];
      }
    }
}

extern "C" void kernel_launch(void* const* d_in, const int* in_sizes, int n_in,
                              void* d_out, int out_size, void* d_ws, size_t ws_size,
                              hipStream_t stream){
  const float* hidden = (const float*)d_in[0];
  const int*   mask   = (const int*)d_in[1];
  const float* probe  = (const float*)d_in[2];
  const float* ipw    = (const float*)d_in[3];
  const float* ipb    = (const float*)d_in[4];
  const float* ow     = (const float*)d_in[5];
  const float* ob     = (const float*)d_in[6];
  const float* ln_g   = (const float*)d_in[7];
  const float* ln_b   = (const float*)d_in[8];
  const float* w1     = (const float*)d_in[9];
  const float* b1     = (const float*)d_in[10];
  const float* w2     = (const float*)d_in[11];
  const float* b2     = (const float*)d_in[12];
  float* out = (float*)d_out;
  float* ws  = (float*)d_ws;

  size_t off = 0;
  float* q  = ws + off; off += E;
  float* qk = ws + off; off += H*E;
  float* cb = ws + off; off += 16;
  float* sc = ws + off; off += (size_t)B*S*H;       // 2097152
  float* part_ml = ws + off; off += 32*32*16*2;     // 32768
  float* ml = ws + off; off += 32*32;

  int slices = 32;
  while (slices > 1){
    size_t need = off + (size_t)B*slices*H*E + (size_t)B*H*E
                + 3*(size_t)B*E + (size_t)B*IDIM;
    if (need*sizeof(float) <= ws_size) break;
    slices >>= 1;
  }
  float* part   = ws + off;  off += (size_t)B*slices*H*E;
  float* ctx    = ws + off;  off += (size_t)B*H*E;
  float* pooled = ws + off;  off += (size_t)B*E;
  float* resid  = ws + off;  off += (size_t)B*E;
  float* x      = ws + off;  off += (size_t)B*E;
  float* h1     = ws + off;

  k_q       <<<288, 256, 0, stream>>>(probe, ipw, ipb, q);
  k_qk      <<<72, 256, 0, stream>>>(q, ipw, ipb, qk, cb);
  k_scores  <<<1024, 256, 0, stream>>>(hidden, qk, cb, mask, sc, part_ml);
  k_mlcomb  <<<1, 512, 0, stream>>>(part_ml, ml);
  k_ctx     <<<32*slices, 256, 0, stream>>>(hidden, sc, ml, part, slices, S/slices);
  k_ctxred  <<<2304, 256, 0, stream>>>(part, ctx, slices);
  k_pool    <<<288, 256, 0, stream>>>(ctx, ipw, ipb, pooled);
  k_outproj <<<288, 256, 0, stream>>>(pooled, ow, ob, resid);
  k_ln      <<<32, 256, 0, stream>>>(resid, ln_g, ln_b, x);
  k_fc1     <<<538, 256, 0, stream>>>(x, w1, b1, h1);
  k_fc2     <<<144, 256, 0, stream>>>(h1, w2, b2, resid, out);
}

// Round 4
// 1118.177 us; speedup vs baseline: 1.6948x; 1.1074x over previous
//
#include <hip/hip_runtime.h>
#include <math.h>

#define E 1152
#define H 16
#define HD 72
#define B 32
#define S 4096
#define IDIM 4304

#define NEGF (-3.402823466e38f)
#define SCALE 0.1178511301977579f  // 1/sqrt(72)

#define GLOAD_LDS16(gp, lp) __builtin_amdgcn_global_load_lds( \
    (const __attribute__((address_space(1))) unsigned int*)(gp), \
    (__attribute__((address_space(3))) unsigned int*)(lp), 16, 0, 0)

__device__ __forceinline__ float wredsum(float v){
  v += __shfl_xor(v,32); v += __shfl_xor(v,16); v += __shfl_xor(v,8);
  v += __shfl_xor(v,4);  v += __shfl_xor(v,2);  v += __shfl_xor(v,1);
  return v;
}

// q[j] = probe . wq[j,:] + bq[j]
__global__ void k_q(const float* __restrict__ probe, const float* __restrict__ ipw,
                    const float* __restrict__ ipb, float* __restrict__ q){
  int tid = threadIdx.x, lane = tid & 63, w = tid >> 6;
  int j = blockIdx.x*4 + w;
  const float* wr = ipw + (size_t)j*E;
  float s = 0.f;
  #pragma unroll
  for (int t=0;t<18;++t){ int e = lane + 64*t; s = fmaf(probe[e], wr[e], s); }
  s = wredsum(s);
  if (lane==0) q[j] = s + ipb[j];
}

// qk[h*E+e] = sum_d q[h*72+d]*wk[h*72+d, e]; cb[h] = q[h]·bk_h
__global__ void k_qk(const float* __restrict__ q, const float* __restrict__ ipw,
                     const float* __restrict__ ipb, float* __restrict__ qk,
                     float* __restrict__ cb){
  int idx = blockIdx.x*256 + threadIdx.x;   // < H*E
  int h = idx / E, e = idx % E;
  float s = 0.f;
  #pragma unroll 8
  for (int d=0; d<HD; ++d)
    s = fmaf(q[h*HD+d], ipw[(size_t)(E + h*HD + d)*E + e], s);
  qk[idx] = s;
  if (idx < H){
    float c = 0.f;
    for (int d=0; d<HD; ++d) c = fmaf(q[idx*HD+d], ipb[E + idx*HD + d], c);
    cb[idx] = c;
  }
}

// ---------------- fused single pass over hidden:
// scores -> online softmax (defer-max THR=8) -> weighted ctx partials.
// grid: 32 b x 32 slices (128 rows each); block = 4 waves; wave owns heads 4w..4w+3.
// outputs: part[b][sl][h][e] (unnormalized, local max), part_ml[(b*32+sl)*16+h]={m,l}
__global__ __launch_bounds__(256) void k_fused(
    const float* __restrict__ hidden, const float* __restrict__ qk,
    const float* __restrict__ cb, const int* __restrict__ mask,
    float* __restrict__ part, float* __restrict__ part_ml){
  __shared__ float tile[8*E];   // 36864 B
  int tid = threadIdx.x, lane = tid & 63, w = tid >> 6;
  int b = blockIdx.x >> 5, sl = blockIdx.x & 31;
  int s0 = sl*128;
  int lb = lane & 0x3C;

  float2 qkr[4][9];
  #pragma unroll
  for (int j=0;j<4;++j){
    const float2* qp = (const float2*)(qk + (size_t)(4*w+j)*E);
    #pragma unroll
    for (int k=0;k<9;++k) qkr[j][k] = qp[lane + 64*k];
  }
  float cbv = cb[4*w + (lane & 3)];
  bool o1 = (lane & 1), o2 = (lane & 2);

  float m = -INFINITY, l = 0.f;
  float2 acc[4][9];
  #pragma unroll
  for (int j=0;j<4;++j)
    #pragma unroll
    for (int k=0;k<9;++k){ acc[j][k].x = 0.f; acc[j][k].y = 0.f; }

  for (int st=0; st<16; ++st){
    __syncthreads();
    {
      const float* src = hidden + ((size_t)b*S + (size_t)(s0 + st*8))*E;
      #pragma unroll
      for (int i=0;i<9;++i){
        int c = i*4 + w;                       // 36 chunks of 64 float4
        GLOAD_LDS16(src + c*256 + lane*4, tile + c*256);
      }
    }
    __syncthreads();
    #pragma unroll
    for (int r=0; r<8; ++r){
      const float2* row = (const float2*)(tile + r*E);
      float2 hv[9];
      #pragma unroll
      for (int k=0;k<9;++k) hv[k] = row[lane + 64*k];

      float a0=0.f, a1=0.f, a2=0.f, a3=0.f;
      #pragma unroll
      for (int k=0;k<9;++k){
        a0 = fmaf(hv[k].x, qkr[0][k].x, fmaf(hv[k].y, qkr[0][k].y, a0));
        a1 = fmaf(hv[k].x, qkr[1][k].x, fmaf(hv[k].y, qkr[1][k].y, a1));
        a2 = fmaf(hv[k].x, qkr[2][k].x, fmaf(hv[k].y, qkr[2][k].y, a2));
        a3 = fmaf(hv[k].x, qkr[3][k].x, fmaf(hv[k].y, qkr[3][k].y, a3));
      }
      // packed butterfly: lanes with lane&3==j end with head (4w+j) full sum
      float c01 = o1 ? a1 : a0, d01 = o1 ? a0 : a1;
      c01 += __shfl_xor(d01, 1);
      float c23 = o1 ? a3 : a2, d23 = o1 ? a2 : a3;
      c23 += __shfl_xor(d23, 1);
      float v = o2 ? c23 : c01, dv = o2 ? c01 : c23;
      v += __shfl_xor(dv, 2);
      v += __shfl_xor(v,4); v += __shfl_xor(v,8);
      v += __shfl_xor(v,16); v += __shfl_xor(v,32);

      int s = s0 + st*8 + r;
      float addm = (1.0f - (float)mask[(size_t)b*S + s]) * NEGF;
      v = SCALE*(v + cbv) + addm;

      // online softmax with deferred max (THR=8)
      if (__any(v > m + 8.0f)){
        float mn = fmaxf(m, v);
        float f  = __expf(m - mn);      // ==1 for heads not exceeding
        m = mn; l *= f;
        float f0 = __shfl(f, lb|0), f1 = __shfl(f, lb|1);
        float f2 = __shfl(f, lb|2), f3 = __shfl(f, lb|3);
        #pragma unroll
        for (int k=0;k<9;++k){
          acc[0][k].x *= f0; acc[0][k].y *= f0;
          acc[1][k].x *= f1; acc[1][k].y *= f1;
          acc[2][k].x *= f2; acc[2][k].y *= f2;
          acc[3][k].x *= f3; acc[3][k].y *= f3;
        }
      }
      float wgt = __expf(v - m);
      l += wgt;
      float w0 = __shfl(wgt, lb|0), w1 = __shfl(wgt, lb|1);
      float w2 = __shfl(wgt, lb|2), w3 = __shfl(wgt, lb|3);
      #pragma unroll
      for (int k=0;k<9;++k){
        acc[0][k].x = fmaf(w0, hv[k].x, acc[0][k].x); acc[0][k].y = fmaf(w0, hv[k].y, acc[0][k].y);
        acc[1][k].x = fmaf(w1, hv[k].x, acc[1][k].x); acc[1][k].y = fmaf(w1, hv[k].y, acc[1][k].y);
        acc[2][k].x = fmaf(w2, hv[k].x, acc[2][k].x); acc[2][k].y = fmaf(w2, hv[k].y, acc[2][k].y);
        acc[3][k].x = fmaf(w3, hv[k].x, acc[3][k].x); acc[3][k].y = fmaf(w3, hv[k].y, acc[3][k].y);
      }
    }
  }
  if (lane < 4){
    size_t o = ((size_t)(b*32 + sl)*16 + 4*w + lane)*2;
    part_ml[o] = m; part_ml[o+1] = l;
  }
  #pragma unroll
  for (int j=0;j<4;++j){
    float2* dst = (float2*)(part + ((size_t)(b*32 + sl)*H + 4*w + j)*E);
    #pragma unroll
    for (int k=0;k<9;++k) dst[lane + 64*k] = acc[j][k];
  }
}

// combine 32 slice-partials -> per-slice final scale = exp(m_sl - M)/L_total
__global__ void k_mlcomb(const float* __restrict__ part_ml, float* __restrict__ scale){
  int t = threadIdx.x;            // 512 = 32*16
  int b = t >> 4, h = t & 15;
  float M = -INFINITY, L = 0.f;
  for (int c = 0; c < 32; ++c){
    size_t o = ((size_t)(b*32 + c)*16 + h)*2;
    float om = part_ml[o], ol = part_ml[o+1];
    float nm = fmaxf(M, om);
    L = L*__expf(M - nm) + ol*__expf(om - nm);
    M = nm;
  }
  float invL = 1.0f / L;
  for (int c = 0; c < 32; ++c){
    size_t o = ((size_t)(b*32 + c)*16 + h)*2;
    scale[(size_t)(b*32 + c)*16 + h] = __expf(part_ml[o] - M) * invL;
  }
}

// ctx[b][h][e] = sum_sl part[b][sl][h][e] * scale[b][sl][h]
__global__ void k_ctxred(const float* __restrict__ part, const float* __restrict__ scale,
                         float* __restrict__ ctx){
  int idx = blockIdx.x*256 + threadIdx.x;  // < B*H*E
  int b = idx / (H*E); int he = idx % (H*E); int h = he / E;
  float s = 0.f;
  for (int sl=0; sl<32; ++sl)
    s = fmaf(part[((size_t)(b*32+sl)*H)*E + he], scale[(size_t)(b*32+sl)*16 + h], s);
  ctx[idx] = s;
}

// pooled[b, j] = wv[j,:]·ctx[b, j/72, :] + bv[j]
__global__ void k_pool(const float* __restrict__ ctx, const float* __restrict__ ipw,
                       const float* __restrict__ ipb, float* __restrict__ pooled){
  int tid = threadIdx.x, lane = tid & 63, w = tid >> 6;
  int j = blockIdx.x*4 + w;
  int h = j / HD;
  const float* wr = ipw + (size_t)2*E*E + (size_t)j*E;
  float acc[32];
  #pragma unroll
  for (int b_=0;b_<32;++b_) acc[b_]=0.f;
  #pragma unroll
  for (int t=0;t<18;++t){
    int e = lane + 64*t;
    float wv = wr[e];
    #pragma unroll
    for (int b_=0;b_<32;++b_)
      acc[b_] = fmaf(wv, ctx[(size_t)(b_*H + h)*E + e], acc[b_]);
  }
  #pragma unroll
  for (int b_=0;b_<32;++b_){
    float s = wredsum(acc[b_]);
    if (lane==b_) pooled[(size_t)b_*E + j] = s + ipb[2*E + j];
  }
}

__global__ void k_outproj(const float* __restrict__ pooled, const float* __restrict__ ow,
                          const float* __restrict__ ob, float* __restrict__ resid){
  int tid = threadIdx.x, lane = tid & 63, w = tid >> 6;
  int i = blockIdx.x*4 + w;
  const float* wr = ow + (size_t)i*E;
  float acc[32];
  #pragma unroll
  for (int b_=0;b_<32;++b_) acc[b_]=0.f;
  #pragma unroll
  for (int t=0;t<18;++t){
    int e = lane + 64*t;
    float wv = wr[e];
    #pragma unroll
    for (int b_=0;b_<32;++b_)
      acc[b_] = fmaf(wv, pooled[(size_t)b_*E + e], acc[b_]);
  }
  #pragma unroll
  for (int b_=0;b_<32;++b_){
    float s = wredsum(acc[b_]);
    if (lane==b_) resid[(size_t)b_*E + i] = s + ob[i];
  }
}

__global__ void k_ln(const float* __restrict__ resid, const float* __restrict__ g,
                     const float* __restrict__ be, float* __restrict__ x){
  __shared__ float red[8];
  int b = blockIdx.x, tid = threadIdx.x, lane = tid & 63, w = tid >> 6;
  const float* r = resid + (size_t)b*E;
  float s = 0.f, s2 = 0.f;
  for (int e=tid; e<E; e+=256){ float v = r[e]; s += v; s2 = fmaf(v,v,s2); }
  s = wredsum(s); s2 = wredsum(s2);
  if (lane==0){ red[w]=s; red[4+w]=s2; }
  __syncthreads();
  float S1 = red[0]+red[1]+red[2]+red[3];
  float S2 = red[4]+red[5]+red[6]+red[7];
  float mu  = S1*(1.0f/E);
  float var = S2*(1.0f/E) - mu*mu;
  float inv = rsqrtf(var + 1e-6f);
  for (int e=tid; e<E; e+=256){
    float v = (r[e]-mu)*inv;
    x[(size_t)b*E + e] = v*g[e] + be[e];
  }
}

__device__ __forceinline__ float gelu_tanh(float u){
  float u3 = u*u*u;
  float t = tanhf(0.7978845608028654f*(u + 0.044715f*u3));
  return 0.5f*u*(1.0f+t);
}

__global__ __launch_bounds__(256) void k_fc1(
    const float* __restrict__ x, const float* __restrict__ w1,
    const float* __restrict__ b1, float* __restrict__ h1){
  int tid = threadIdx.x, lane = tid & 63, w = tid >> 6;
  int wid = blockIdx.x*4 + w;      // < 2152
  int i0 = wid*2;
  float acc[2][32];
  #pragma unroll
  for (int ii=0;ii<2;++ii)
    #pragma unroll
    for (int b_=0;b_<32;++b_) acc[ii][b_]=0.f;
  #pragma unroll
  for (int t=0;t<18;++t){
    int e = lane + 64*t;
    float f0 = w1[(size_t)i0*E + e];
    float f1 = w1[(size_t)(i0+1)*E + e];
    #pragma unroll
    for (int b_=0;b_<32;++b_){
      float xv = x[(size_t)b_*E + e];
      acc[0][b_] = fmaf(f0, xv, acc[0][b_]);
      acc[1][b_] = fmaf(f1, xv, acc[1][b_]);
    }
  }
  #pragma unroll
  for (int ii=0;ii<2;++ii)
    #pragma unroll
    for (int b_=0;b_<32;++b_){
      float s = wredsum(acc[ii][b_]);
      if (lane==b_) h1[(size_t)b_*IDIM + i0 + ii] = gelu_tanh(s + b1[i0+ii]);
    }
}

__global__ __launch_bounds__(256) void k_fc2(
    const float* __restrict__ h1, const float* __restrict__ w2,
    const float* __restrict__ b2, const float* __restrict__ resid,
    float* __restrict__ out){
  int tid = threadIdx.x, lane = tid & 63, w = tid >> 6;
  int wid = blockIdx.x*4 + w;      // < 576
  int i0 = wid*2;
  float acc[2][32];
  #pragma unroll
  for (int ii=0;ii<2;++ii)
    #pragma unroll
    for (int b_=0;b_<32;++b_) acc[ii][b_]=0.f;
  #pragma unroll 2
  for (int t=0;t<68;++t){
    int e = lane + 64*t;
    if (e < IDIM){
      float f0 = w2[(size_t)i0*IDIM + e];
      float f1 = w2[(size_t)(i0+1)*IDIM + e];
      #pragma unroll
      for (int b_=0;b_<32;++b_){
        float hvv = h1[(size_t)b_*IDIM + e];
        acc[0][b_] = fmaf(f0, hvv, acc[0][b_]);
        acc[1][b_] = fmaf(f1, hvv, acc[1][b_]);
      }
    }
  }
  #pragma unroll
  for (int ii=0;ii<2;++ii)
    #pragma unroll
    for (int b_=0;b_<32;++b_){
      float s = wredsum(acc[ii][b_]);
      if (lane==b_){
        int i = i0 + ii;
        out[(size_t)b_*E + i] = resid[(size_t)b_*E + i] + s + b2[i];
      }
    }
}

extern "C" void kernel_launch(void* const* d_in, const int* in_sizes, int n_in,
                              void* d_out, int out_size, void* d_ws, size_t ws_size,
                              hipStream_t stream){
  const float* hidden = (const float*)d_in[0];
  const int*   mask   = (const int*)d_in[1];
  const float* probe  = (const float*)d_in[2];
  const float* ipw    = (const float*)d_in[3];
  const float* ipb    = (const float*)d_in[4];
  const float* ow     = (const float*)d_in[5];
  const float* ob     = (const float*)d_in[6];
  const float* ln_g   = (const float*)d_in[7];
  const float* ln_b   = (const float*)d_in[8];
  const float* w1     = (const float*)d_in[9];
  const float* b1     = (const float*)d_in[10];
  const float* w2     = (const float*)d_in[11];
  const float* b2     = (const float*)d_in[12];
  float* out = (float*)d_out;
  float* ws  = (float*)d_ws;

  size_t off = 0;
  float* q  = ws + off; off += E;
  float* qk = ws + off; off += H*E;
  float* cb = ws + off; off += 16;
  float* part_ml = ws + off; off += 32*32*16*2;     // 32768
  float* scale   = ws + off; off += 32*32*16;       // 16384
  float* part    = ws + off; off += (size_t)B*32*H*E;  // 75.5 MB
  float* ctx     = ws + off; off += (size_t)B*H*E;
  float* pooled  = ws + off; off += (size_t)B*E;
  float* resid   = ws + off; off += (size_t)B*E;
  float* x       = ws + off; off += (size_t)B*E;
  float* h1      = ws + off;

  k_q       <<<288, 256, 0, stream>>>(probe, ipw, ipb, q);
  k_qk      <<<72, 256, 0, stream>>>(q, ipw, ipb, qk, cb);
  k_fused   <<<1024, 256, 0, stream>>>(hidden, qk, cb, mask, part, part_ml);
  k_mlcomb  <<<1, 512, 0, stream>>>(part_ml, scale);
  k_ctxred  <<<2304, 256, 0, stream>>>(part, scale, ctx);
  k_pool    <<<288, 256, 0, stream>>>(ctx, ipw, ipb, pooled);
  k_outproj <<<288, 256, 0, stream>>>(pooled, ow, ob, resid);
  k_ln      <<<32, 256, 0, stream>>>(resid, ln_g, ln_b, x);
  k_fc1     <<<538, 256, 0, stream>>>(x, w1, b1, h1);
  k_fc2     <<<144, 256, 0, stream>>>(h1, w2, b2, resid, out);
}